// Round 10
// baseline (5890.542 us; speedup 1.0000x reference)
//
#include <hip/hip_runtime.h>
#include <hip/hip_bf16.h>

#define NS 4096
#define SEQ 2048
#define NBLK 256
#define THR 1024
#define NT 1023  // pair transitions: s_{2u} -> s_{2u+2}
#define SEN 0xAAAAAAAAu

typedef unsigned short ushort_t;
typedef float vfloat2 __attribute__((ext_vector_type(2)));
typedef float f32x4 __attribute__((ext_vector_type(4)));

__device__ __forceinline__ float wred_sum(float v) {
#pragma unroll
  for (int o = 32; o > 0; o >>= 1) v += __shfl_xor(v, o, 64);
  return v;
}
__device__ __forceinline__ float wred_max(float v) {
#pragma unroll
  for (int o = 32; o > 0; o >>= 1) v = fmaxf(v, __shfl_xor(v, o, 64));
  return v;
}

// ---- fp8 e4m3fn helpers (positive values only) ----
#if __has_builtin(__builtin_amdgcn_cvt_pk_f32_fp8)
template <bool W>
__device__ __forceinline__ vfloat2 cvtpk(unsigned d) {
  return __builtin_amdgcn_cvt_pk_f32_fp8((int)d, W);
}
#else
template <bool W>
__device__ __forceinline__ vfloat2 cvtpk(unsigned d) {
  unsigned b0 = (d >> (W ? 16 : 0)) & 0x7fu;
  unsigned b1 = (d >> (W ? 24 : 8)) & 0x7fu;
  vfloat2 r;
  r.x = __uint_as_float((b0 << 20) + 0x3C000000u);
  r.y = __uint_as_float((b1 << 20) + 0x3C000000u);
  return r;
}
#endif

__device__ __forceinline__ unsigned char encf(float w) {
  float v = fminf(fmaxf(w, 0.0157f), 440.0f);
  unsigned u = __float_as_uint(v);
  return (unsigned char)(((u + 0xC4080000u) >> 20) & 0x7Fu);
}

__device__ __forceinline__ float dot4_fp8(unsigned d, float4 s, float acc) {
  vfloat2 lo = cvtpk<false>(d);
  vfloat2 hi = cvtpk<true>(d);
  acc += s.x * lo.x; acc += s.y * lo.y;
  acc += s.z * hi.x; acc += s.w * hi.y;
  return acc;
}

// ---- per-row softmax stats of T; rstat.y = 4096/sum ----
__global__ void rowstats_kernel(const float* __restrict__ T, float2* __restrict__ rstat) {
  const int r = blockIdx.x;
  const float* row = T + (size_t)r * NS;
  const int tid = threadIdx.x;
  float4 v[4];
  float mx = -1e30f;
#pragma unroll
  for (int q = 0; q < 4; ++q) {
    v[q] = *(const float4*)(row + q * 1024 + tid * 4);
    mx = fmaxf(mx, fmaxf(fmaxf(v[q].x, v[q].y), fmaxf(v[q].z, v[q].w)));
  }
  __shared__ float redm[4], reds[4];
  mx = wred_max(mx);
  if ((tid & 63) == 0) redm[tid >> 6] = mx;
  __syncthreads();
  mx = fmaxf(fmaxf(redm[0], redm[1]), fmaxf(redm[2], redm[3]));
  float se = 0.f;
#pragma unroll
  for (int q = 0; q < 4; ++q)
    se += __expf(v[q].x - mx) + __expf(v[q].y - mx) + __expf(v[q].z - mx) + __expf(v[q].w - mx);
  se = wred_sum(se);
  if ((tid & 63) == 0) reds[tid >> 6] = se;
  __syncthreads();
  if (tid == 0) {
    float tot = reds[0] + reds[1] + reds[2] + reds[3];
    rstat[r] = make_float2(mx, 4096.0f / tot);
  }
}

// ---- build R_s fp8: R[j][k] = enc(Tn[k,s,j]*4096) ----
__global__ void buildR_kernel(const float* __restrict__ T, const float2* __restrict__ rstat,
                              unsigned char* __restrict__ R, int s) {
  const int j = blockIdx.x * 256 + threadIdx.x;
  const int i0 = blockIdx.y * 16;
  unsigned char ob[16] __attribute__((aligned(16)));
#pragma unroll
  for (int ii = 0; ii < 16; ++ii) {
    const int r = (i0 + ii) * 2 + s;
    const float2 st = rstat[r];
    const float w = __expf(T[(size_t)r * NS + j] - st.x) * st.y;
    ob[ii] = encf(w);
  }
  *(uint4*)(R + (size_t)j * NS + i0) = *(uint4*)ob;
}

// ---- build M_s fp8: M[i][k] = enc(Tn[i,s,k]*4096) ----
__global__ void buildM_kernel(const float* __restrict__ T, const float2* __restrict__ rstat,
                              unsigned char* __restrict__ M, int s) {
  const int i = blockIdx.x;
  const int r = i * 2 + s;
  const float2 st = rstat[r];
  const int k0 = threadIdx.x * 16;
  unsigned char ob[16] __attribute__((aligned(16)));
#pragma unroll
  for (int kk = 0; kk < 16; ++kk) {
    const float w = __expf(T[(size_t)r * NS + k0 + kk] - st.x) * st.y;
    ob[kk] = encf(w);
  }
  *(uint4*)(M + (size_t)i * NS + k0) = *(uint4*)ob;
}

// ---- pair GEMM: C[j][i] = enc( (1/4096) * sum_k A[j][k]*B[i][k] ) ----
// Register double-buffered K-loop: load k+32 while MFMA on k.
__global__ void __launch_bounds__(256)
pairgemm_kernel(const unsigned char* __restrict__ A, const unsigned char* __restrict__ B,
                unsigned char* __restrict__ C) {
  const int tid = threadIdx.x;
  const int lane = tid & 63;
  const int wv = tid >> 6;
  const int j0 = blockIdx.y * 128 + (wv >> 1) * 64;
  const int i0 = blockIdx.x * 128 + (wv & 1) * 64;
  const int lrow = lane & 15;
  const int lkg = (lane >> 4) * 8;

  f32x4 acc[4][4] = {};
  const unsigned char* Ab = A + (size_t)(j0 + lrow) * NS + lkg;
  const unsigned char* Bb = B + (size_t)(i0 + lrow) * NS + lkg;
  long long a0[4], b0[4], a1[4], b1[4];
#pragma unroll
  for (int m = 0; m < 4; ++m) {
    a0[m] = *(const long long*)(Ab + (size_t)(m * 16) * NS);
    b0[m] = *(const long long*)(Bb + (size_t)(m * 16) * NS);
  }
  for (int kc = 0; kc < NS; kc += 64) {
#pragma unroll
    for (int m = 0; m < 4; ++m) {
      a1[m] = *(const long long*)(Ab + (size_t)(m * 16) * NS + kc + 32);
      b1[m] = *(const long long*)(Bb + (size_t)(m * 16) * NS + kc + 32);
    }
#pragma unroll
    for (int m = 0; m < 4; ++m)
#pragma unroll
      for (int n = 0; n < 4; ++n)
        acc[m][n] = __builtin_amdgcn_mfma_f32_16x16x32_fp8_fp8(a0[m], b0[n], acc[m][n], 0, 0, 0);
    // prefetch next iteration's first half (last-iter reads spill <64B into
    // the adjacent mapped ws region and are never consumed)
#pragma unroll
    for (int m = 0; m < 4; ++m) {
      a0[m] = *(const long long*)(Ab + (size_t)(m * 16) * NS + kc + 64);
      b0[m] = *(const long long*)(Bb + (size_t)(m * 16) * NS + kc + 64);
    }
#pragma unroll
    for (int m = 0; m < 4; ++m)
#pragma unroll
      for (int n = 0; n < 4; ++n)
        acc[m][n] = __builtin_amdgcn_mfma_f32_16x16x32_fp8_fp8(a1[m], b1[n], acc[m][n], 0, 0, 0);
  }
  const int orow = (lane >> 4) * 4;
#pragma unroll
  for (int m = 0; m < 4; ++m)
#pragma unroll
    for (int n = 0; n < 4; ++n)
#pragma unroll
      for (int r = 0; r < 4; ++r) {
        const int j = j0 + m * 16 + orow + r;
        const int i = i0 + n * 16 + lrow;
        C[(size_t)j * NS + i] = encf(acc[m][n][r] * (1.0f / 4096.0f));
      }
}

// ---- in-place per-row byte permute into the scan's layout ----
__global__ void permq8_kernel(unsigned char* __restrict__ Q) {
  unsigned char* row = Q + ((size_t)blockIdx.y * NS + blockIdx.x) * NS;
  const int t = threadIdx.x;
  const int q = t >> 6, l = t & 63;
  uint4 o;
  o.x = *(const unsigned*)(row + q * 1024 + 0 * 256 + l * 4);
  o.y = *(const unsigned*)(row + q * 1024 + 1 * 256 + l * 4);
  o.z = *(const unsigned*)(row + q * 1024 + 2 * 256 + l * 4);
  o.w = *(const unsigned*)(row + q * 1024 + 3 * 256 + l * 4);
  *(uint4*)(row + q * 1024 + l * 16) = o;
}

// ---- normalize O (f32) ----
__global__ void onnorm_kernel(const float* __restrict__ O, float* __restrict__ On) {
  const int r = blockIdx.x * blockDim.x + threadIdx.x;
  if (r >= NS * 2) return;
  float4 v = *(const float4*)(O + (size_t)r * 4);
  float mx = fmaxf(fmaxf(v.x, v.y), fmaxf(v.z, v.w));
  float e0 = __expf(v.x - mx), e1 = __expf(v.y - mx), e2 = __expf(v.z - mx), e3 = __expf(v.w - mx);
  float inv = 1.0f / (e0 + e1 + e2 + e3);
  *(float4*)(On + (size_t)r * 4) = make_float4(e0 * inv, e1 * inv, e2 * inv, e3 * inv);
}

// ---- E_{a,b}[i][c] = sum_k Tn[i,a,k] * On[k,b,c] ----
__global__ void emat_kernel(const float* __restrict__ T, const float2* __restrict__ rstat,
                            const float* __restrict__ On, float* __restrict__ E) {
  const int i = blockIdx.x, a = blockIdx.y;
  const int r = i * 2 + a;
  const float2 st = rstat[r];
  const int tid = threadIdx.x;
  float e0[4] = {}, e1[4] = {};
  for (int q = 0; q < 16; ++q) {
    const int k = q * 256 + tid;
    const float w = __expf(T[(size_t)r * NS + k] - st.x) * st.y * (1.0f / 4096.0f);
    const float4 o0 = *(const float4*)(On + (size_t)(k * 2 + 0) * 4);
    const float4 o1 = *(const float4*)(On + (size_t)(k * 2 + 1) * 4);
    e0[0] += w * o0.x; e0[1] += w * o0.y; e0[2] += w * o0.z; e0[3] += w * o0.w;
    e1[0] += w * o1.x; e1[1] += w * o1.y; e1[2] += w * o1.z; e1[3] += w * o1.w;
  }
  __shared__ float red[4][8];
  const int lane = tid & 63, wave = tid >> 6;
#pragma unroll
  for (int c = 0; c < 4; ++c) { e0[c] = wred_sum(e0[c]); e1[c] = wred_sum(e1[c]); }
  if (lane == 0) {
#pragma unroll
    for (int c = 0; c < 4; ++c) { red[wave][c] = e0[c]; red[wave][4 + c] = e1[c]; }
  }
  __syncthreads();
  if (tid == 0) {
    float f0[4], f1[4];
#pragma unroll
    for (int c = 0; c < 4; ++c) {
      f0[c] = red[0][c] + red[1][c] + red[2][c] + red[3][c];
      f1[c] = red[0][4 + c] + red[1][4 + c] + red[2][4 + c] + red[3][4 + c];
    }
    *(float4*)(E + ((size_t)(a * 2 + 0) * NS + i) * 4) = make_float4(f0[0], f0[1], f0[2], f0[3]);
    *(float4*)(E + ((size_t)(a * 2 + 1) * NS + i) * 4) = make_float4(f1[0], f1[1], f1[2], f1[3]);
  }
}

// ---- s0 = softmax(init) * 4096 ----
__global__ void initstate_kernel(const float* __restrict__ init, float* __restrict__ s0) {
  const int tid = threadIdx.x;
  float4 v = *(const float4*)(init + tid * 4);
  float mx = fmaxf(fmaxf(v.x, v.y), fmaxf(v.z, v.w));
  __shared__ float red[16];
  mx = wred_max(mx);
  if ((tid & 63) == 0) red[tid >> 6] = mx;
  __syncthreads();
  float MX = -1e30f;
#pragma unroll
  for (int k = 0; k < 16; ++k) MX = fmaxf(MX, red[k]);
  __syncthreads();
  float e0 = __expf(v.x - MX), e1 = __expf(v.y - MX), e2 = __expf(v.z - MX), e3 = __expf(v.w - MX);
  float se = wred_sum(e0 + e1 + e2 + e3);
  if ((tid & 63) == 0) red[tid >> 6] = se;
  __syncthreads();
  float tot = 0.f;
#pragma unroll
  for (int k = 0; k < 16; ++k) tot += red[k];
  float inv = 4096.0f / tot;
  *(float4*)(s0 + tid * 4) = make_float4(e0 * inv, e1 * inv, e2 * inv, e3 * inv);
}

// ---- fill states rows 1..1023 with sentinel (fresh each launch) ----
__global__ void fillsent_kernel(float* __restrict__ states) {
  float* row = states + (size_t)(blockIdx.x + 1) * NS;
  *(uint4*)(row + threadIdx.x * 4) = make_uint4(SEN, SEN, SEN, SEN);
}

// ---- K3: pair-fused scan, sentinel-poll + LDS fan-out.
// wave w = (g = w>>2, cg = w&3). Only cg==0 waves poll (sentinel, L2-bypass
// loads of slice g = 1024 floats), then stage the slice into LDS. All 16
// waves compute their 4 cols x slice-g quarter-dot from LDS; partials
// reduced via LDS; wave0 lanes 0-15 store the 16 cols (WT agent atomics).
// Per-dword sentinel monotonicity -> no fences anywhere.
__global__ void __launch_bounds__(THR, 4)
scan_kernel(const unsigned char* __restrict__ Pt8, const int* __restrict__ seq,
            float* __restrict__ states) {
  __shared__ __align__(16) float smem[NS];
  __shared__ __align__(16) float partial[16][4];
  __shared__ int spid[1024];
  const int tid = threadIdx.x;
  const int lane = tid & 63;
  const int wave = tid >> 6;
  const int blk = blockIdx.x;
  const int g = wave >> 2;
  const int cg = wave & 3;
  const int colbase = blk * 16 + cg * 4;

  spid[tid] = seq[2 * tid] * 2 + seq[2 * tid + 1];
  __syncthreads();

  uint4 qa0, qa1, qa2, qa3, qb0, qb1, qb2, qb3;
  {
    const unsigned char* mb = Pt8 + ((size_t)spid[0] * NS + colbase) * NS + g * 1024 + lane * 16;
    qa0 = *(const uint4*)mb;
    qa1 = *(const uint4*)(mb + NS);
    qa2 = *(const uint4*)(mb + 2 * NS);
    qa3 = *(const uint4*)(mb + 3 * NS);
  }

  for (int u = 0; u < NT; ++u) {
    // prefetch next round's matrix columns (cached; L2-resident after 1st use)
    if (u + 1 < NT) {
      const unsigned char* mb =
          Pt8 + ((size_t)spid[u + 1] * NS + colbase) * NS + g * 1024 + lane * 16;
      qb0 = *(const uint4*)mb;
      qb1 = *(const uint4*)(mb + NS);
      qb2 = *(const uint4*)(mb + 2 * NS);
      qb3 = *(const uint4*)(mb + 3 * NS);
    }

    // cg==0 waves: sentinel-poll slice g of row u, stage into LDS.
    // (u=0: init row has no sentinel -> exits first iteration.)
    if (cg == 0) {
      const unsigned long long sb =
          (unsigned long long)(states + (size_t)u * NS + g * 1024 + lane * 4);
      uint4 s0, s1, s2, s3;
      for (;;) {
        asm volatile("global_load_dwordx4 %0, %1, off sc0 sc1" : "=v"(s0) : "v"(sb) : "memory");
        asm volatile("global_load_dwordx4 %0, %1, off offset:1024 sc0 sc1" : "=v"(s1) : "v"(sb) : "memory");
        asm volatile("global_load_dwordx4 %0, %1, off offset:2048 sc0 sc1" : "=v"(s2) : "v"(sb) : "memory");
        asm volatile("global_load_dwordx4 %0, %1, off offset:3072 sc0 sc1" : "=v"(s3) : "v"(sb) : "memory");
        asm volatile("s_waitcnt vmcnt(0)" ::: "memory");
        __builtin_amdgcn_sched_barrier(0);  // rule-18: no consumer above the wait
        bool ok = (s0.x != SEN) & (s0.y != SEN) & (s0.z != SEN) & (s0.w != SEN) &
                  (s1.x != SEN) & (s1.y != SEN) & (s1.z != SEN) & (s1.w != SEN) &
                  (s2.x != SEN) & (s2.y != SEN) & (s2.z != SEN) & (s2.w != SEN) &
                  (s3.x != SEN) & (s3.y != SEN) & (s3.z != SEN) & (s3.w != SEN);
        if (__all(ok)) break;
        __builtin_amdgcn_s_sleep(2);
      }
      *(uint4*)(smem + g * 1024 + 0 * 256 + lane * 4) = s0;
      *(uint4*)(smem + g * 1024 + 1 * 256 + lane * 4) = s1;
      *(uint4*)(smem + g * 1024 + 2 * 256 + lane * 4) = s2;
      *(uint4*)(smem + g * 1024 + 3 * 256 + lane * 4) = s3;
    }
    __syncthreads();

    // compute from LDS (conflict-free: consecutive lanes -> consecutive 16B)
    const float4 f0 = *(const float4*)(smem + g * 1024 + 0 * 256 + lane * 4);
    const float4 f1 = *(const float4*)(smem + g * 1024 + 1 * 256 + lane * 4);
    const float4 f2 = *(const float4*)(smem + g * 1024 + 2 * 256 + lane * 4);
    const float4 f3 = *(const float4*)(smem + g * 1024 + 3 * 256 + lane * 4);

    float a0 = 0.f, a1 = 0.f, a2 = 0.f, a3 = 0.f;
    a0 = dot4_fp8(qa0.x, f0, a0); a0 = dot4_fp8(qa0.y, f1, a0);
    a0 = dot4_fp8(qa0.z, f2, a0); a0 = dot4_fp8(qa0.w, f3, a0);
    a1 = dot4_fp8(qa1.x, f0, a1); a1 = dot4_fp8(qa1.y, f1, a1);
    a1 = dot4_fp8(qa1.z, f2, a1); a1 = dot4_fp8(qa1.w, f3, a1);
    a2 = dot4_fp8(qa2.x, f0, a2); a2 = dot4_fp8(qa2.y, f1, a2);
    a2 = dot4_fp8(qa2.z, f2, a2); a2 = dot4_fp8(qa2.w, f3, a2);
    a3 = dot4_fp8(qa3.x, f0, a3); a3 = dot4_fp8(qa3.y, f1, a3);
    a3 = dot4_fp8(qa3.z, f2, a3); a3 = dot4_fp8(qa3.w, f3, a3);

    a0 = wred_sum(a0); a1 = wred_sum(a1); a2 = wred_sum(a2); a3 = wred_sum(a3);
    if (lane == 0) *(float4*)(&partial[wave][0]) = make_float4(a0, a1, a2, a3);
    __syncthreads();
    if (tid < 16) {
      const int cgx = tid >> 2, j = tid & 3;
      const float r = partial[0 * 4 + cgx][j] + partial[1 * 4 + cgx][j] +
                      partial[2 * 4 + cgx][j] + partial[3 * 4 + cgx][j];
      __hip_atomic_store(&states[(size_t)(u + 1) * NS + blk * 16 + tid],
                         r * (1.0f / 4096.0f), __ATOMIC_RELAXED, __HIP_MEMORY_SCOPE_AGENT);
    }
    qa0 = qb0; qa1 = qb1; qa2 = qb2; qa3 = qb3;
  }
}

// ---- K4: even t: out = (s_u @ On[:,y])/mass; odd: (s_u @ E_ab)/mass ----
__global__ void output_kernel(const float* __restrict__ states, const float* __restrict__ On,
                              const float* __restrict__ E, const int* __restrict__ seq,
                              float* __restrict__ out) {
  const int t = blockIdx.x;
  const int y = seq[t];
  const int u = t >> 1;
  const bool odd = t & 1;
  const float* s = states + (size_t)u * NS;
  const float4* W = odd ? (const float4*)(E + ((size_t)(seq[t - 1] * 2 + y) * NS) * 4) : nullptr;
  const float4* Onf = (const float4*)On;
  const int tid = threadIdx.x;
  float a0 = 0, a1 = 0, a2 = 0, a3 = 0, mass = 0;
  for (int q = 0; q < 16; ++q) {
    const int i = q * 256 + tid;
    const float sv = s[i];
    const float4 w = odd ? W[i] : Onf[i * 2 + y];
    a0 += sv * w.x; a1 += sv * w.y; a2 += sv * w.z; a3 += sv * w.w; mass += sv;
  }
  a0 = wred_sum(a0); a1 = wred_sum(a1); a2 = wred_sum(a2); a3 = wred_sum(a3);
  mass = wred_sum(mass);
  __shared__ float red[4][5];
  const int lane = tid & 63, wave = tid >> 6;
  if (lane == 0) { red[wave][0] = a0; red[wave][1] = a1; red[wave][2] = a2;
                   red[wave][3] = a3; red[wave][4] = mass; }
  __syncthreads();
  if (tid == 0) {
    float b0 = red[0][0] + red[1][0] + red[2][0] + red[3][0];
    float b1 = red[0][1] + red[1][1] + red[2][1] + red[3][1];
    float b2 = red[0][2] + red[1][2] + red[2][2] + red[3][2];
    float b3 = red[0][3] + red[1][3] + red[2][3] + red[3][3];
    float M  = red[0][4] + red[1][4] + red[2][4] + red[3][4];
    const float inv = 1.0f / M;
    *(float4*)(out + (size_t)t * 4) = make_float4(b0 * inv, b1 * inv, b2 * inv, b3 * inv);
  }
}

extern "C" void kernel_launch(void* const* d_in, const int* in_sizes, int n_in,
                              void* d_out, int out_size, void* d_ws, size_t ws_size,
                              hipStream_t stream) {
  const int* seq    = (const int*)d_in[0];
  const float* T    = (const float*)d_in[1];
  const float* O    = (const float*)d_in[2];
  const float* init = (const float*)d_in[3];
  float* out = (float*)d_out;

  char* ws = (char*)d_ws;
  unsigned char* Rcur = (unsigned char*)ws;
  unsigned char* Mcur = (unsigned char*)(ws + 16777216);
  unsigned char* Q8   = (unsigned char*)(ws + 33554432);
  float* states = (float*)ws;  // overlays Rcur/Mcur after GEMMs
  char* sm = ws + 100663296;
  float* On      = (float*)(sm);
  float2* rstat  = (float2*)(sm + 131072);
  float* E       = (float*)(sm + 131072 + 65536);

  hipLaunchKernelGGL(rowstats_kernel, dim3(NS * 2), dim3(256), 0, stream, T, rstat);
  hipLaunchKernelGGL(onnorm_kernel, dim3(32), dim3(256), 0, stream, O, On);

  hipLaunchKernelGGL(buildR_kernel, dim3(16, 256), dim3(256), 0, stream, T, rstat, Rcur, 0);
  hipLaunchKernelGGL(buildM_kernel, dim3(NS), dim3(256), 0, stream, T, rstat, Mcur, 0);
  hipLaunchKernelGGL(pairgemm_kernel, dim3(32, 32), dim3(256), 0, stream, Rcur, Mcur,
                     Q8 + (size_t)0 * 16777216);  // a=0,b=0
  hipLaunchKernelGGL(buildM_kernel, dim3(NS), dim3(256), 0, stream, T, rstat, Mcur, 1);
  hipLaunchKernelGGL(pairgemm_kernel, dim3(32, 32), dim3(256), 0, stream, Rcur, Mcur,
                     Q8 + (size_t)2 * 16777216);  // a=1,b=0
  hipLaunchKernelGGL(buildR_kernel, dim3(16, 256), dim3(256), 0, stream, T, rstat, Rcur, 1);
  hipLaunchKernelGGL(buildM_kernel, dim3(NS), dim3(256), 0, stream, T, rstat, Mcur, 0);
  hipLaunchKernelGGL(pairgemm_kernel, dim3(32, 32), dim3(256), 0, stream, Rcur, Mcur,
                     Q8 + (size_t)1 * 16777216);  // a=0,b=1
  hipLaunchKernelGGL(buildM_kernel, dim3(NS), dim3(256), 0, stream, T, rstat, Mcur, 1);
  hipLaunchKernelGGL(pairgemm_kernel, dim3(32, 32), dim3(256), 0, stream, Rcur, Mcur,
                     Q8 + (size_t)3 * 16777216);  // a=1,b=1

  hipLaunchKernelGGL(permq8_kernel, dim3(NS, 4), dim3(256), 0, stream, Q8);
  hipLaunchKernelGGL(emat_kernel, dim3(NS, 2), dim3(256), 0, stream, T, rstat, On, E);
  hipLaunchKernelGGL(fillsent_kernel, dim3(NT), dim3(1024), 0, stream, states);
  hipLaunchKernelGGL(initstate_kernel, dim3(1), dim3(1024), 0, stream, init, states);

  void* kargs[] = { (void*)&Q8, (void*)&seq, (void*)&states };
  (void)hipLaunchCooperativeKernel((void*)scan_kernel, dim3(NBLK), dim3(THR),
                                   kargs, 0, stream);

  hipLaunchKernelGGL(output_kernel, dim3(SEQ), dim3(256), 0, stream, states, On, E, seq, out);
}

// Round 11
// 5230.396 us; speedup vs baseline: 1.1262x; 1.1262x over previous
//
#include <hip/hip_runtime.h>
#include <hip/hip_bf16.h>

#define NS 4096
#define SEQ 2048
#define NBLK 256
#define THR 1024
#define NT 1023  // pair transitions: s_{2u} -> s_{2u+2}

typedef unsigned short ushort_t;
typedef float vfloat2 __attribute__((ext_vector_type(2)));
typedef float f32x4 __attribute__((ext_vector_type(4)));

__device__ __forceinline__ float wred_sum(float v) {
#pragma unroll
  for (int o = 32; o > 0; o >>= 1) v += __shfl_xor(v, o, 64);
  return v;
}
__device__ __forceinline__ float wred_max(float v) {
#pragma unroll
  for (int o = 32; o > 0; o >>= 1) v = fmaxf(v, __shfl_xor(v, o, 64));
  return v;
}

// ---- fp8 e4m3fn helpers (positive values only) ----
#if __has_builtin(__builtin_amdgcn_cvt_pk_f32_fp8)
template <bool W>
__device__ __forceinline__ vfloat2 cvtpk(unsigned d) {
  return __builtin_amdgcn_cvt_pk_f32_fp8((int)d, W);
}
#else
template <bool W>
__device__ __forceinline__ vfloat2 cvtpk(unsigned d) {
  unsigned b0 = (d >> (W ? 16 : 0)) & 0x7fu;
  unsigned b1 = (d >> (W ? 24 : 8)) & 0x7fu;
  vfloat2 r;
  r.x = __uint_as_float((b0 << 20) + 0x3C000000u);
  r.y = __uint_as_float((b1 << 20) + 0x3C000000u);
  return r;
}
#endif

__device__ __forceinline__ unsigned char encf(float w) {
  float v = fminf(fmaxf(w, 0.0157f), 440.0f);
  unsigned u = __float_as_uint(v);
  return (unsigned char)(((u + 0xC4080000u) >> 20) & 0x7Fu);
}

__device__ __forceinline__ float dot4_fp8(unsigned d, float4 s, float acc) {
  vfloat2 lo = cvtpk<false>(d);
  vfloat2 hi = cvtpk<true>(d);
  acc += s.x * lo.x; acc += s.y * lo.y;
  acc += s.z * hi.x; acc += s.w * hi.y;
  return acc;
}

// ---- per-row softmax stats of T; rstat.y = 4096/sum ----
__global__ void rowstats_kernel(const float* __restrict__ T, float2* __restrict__ rstat) {
  const int r = blockIdx.x;
  const float* row = T + (size_t)r * NS;
  const int tid = threadIdx.x;
  float4 v[4];
  float mx = -1e30f;
#pragma unroll
  for (int q = 0; q < 4; ++q) {
    v[q] = *(const float4*)(row + q * 1024 + tid * 4);
    mx = fmaxf(mx, fmaxf(fmaxf(v[q].x, v[q].y), fmaxf(v[q].z, v[q].w)));
  }
  __shared__ float redm[4], reds[4];
  mx = wred_max(mx);
  if ((tid & 63) == 0) redm[tid >> 6] = mx;
  __syncthreads();
  mx = fmaxf(fmaxf(redm[0], redm[1]), fmaxf(redm[2], redm[3]));
  float se = 0.f;
#pragma unroll
  for (int q = 0; q < 4; ++q)
    se += __expf(v[q].x - mx) + __expf(v[q].y - mx) + __expf(v[q].z - mx) + __expf(v[q].w - mx);
  se = wred_sum(se);
  if ((tid & 63) == 0) reds[tid >> 6] = se;
  __syncthreads();
  if (tid == 0) {
    float tot = reds[0] + reds[1] + reds[2] + reds[3];
    rstat[r] = make_float2(mx, 4096.0f / tot);
  }
}

// ---- build R_s fp8: R[j][k] = enc(Tn[k,s,j]*4096) ----
__global__ void buildR_kernel(const float* __restrict__ T, const float2* __restrict__ rstat,
                              unsigned char* __restrict__ R, int s) {
  const int j = blockIdx.x * 256 + threadIdx.x;
  const int i0 = blockIdx.y * 16;
  unsigned char ob[16] __attribute__((aligned(16)));
#pragma unroll
  for (int ii = 0; ii < 16; ++ii) {
    const int r = (i0 + ii) * 2 + s;
    const float2 st = rstat[r];
    const float w = __expf(T[(size_t)r * NS + j] - st.x) * st.y;
    ob[ii] = encf(w);
  }
  *(uint4*)(R + (size_t)j * NS + i0) = *(uint4*)ob;
}

// ---- build M_s fp8: M[i][k] = enc(Tn[i,s,k]*4096) ----
__global__ void buildM_kernel(const float* __restrict__ T, const float2* __restrict__ rstat,
                              unsigned char* __restrict__ M, int s) {
  const int i = blockIdx.x;
  const int r = i * 2 + s;
  const float2 st = rstat[r];
  const int k0 = threadIdx.x * 16;
  unsigned char ob[16] __attribute__((aligned(16)));
#pragma unroll
  for (int kk = 0; kk < 16; ++kk) {
    const float w = __expf(T[(size_t)r * NS + k0 + kk] - st.x) * st.y;
    ob[kk] = encf(w);
  }
  *(uint4*)(M + (size_t)i * NS + k0) = *(uint4*)ob;
}

// ---- GEMM body: C[j][i] = enc( (1/4096) * sum_k A[j][k]*B[i][k] ) ----
__device__ __forceinline__ void pairgemm_body(const unsigned char* __restrict__ A,
                                              const unsigned char* __restrict__ B,
                                              unsigned char* __restrict__ C,
                                              int bx, int by) {
  const int tid = threadIdx.x;
  const int lane = tid & 63;
  const int wv = tid >> 6;
  const int j0 = by * 128 + (wv >> 1) * 64;
  const int i0 = bx * 128 + (wv & 1) * 64;
  const int lrow = lane & 15;
  const int lkg = (lane >> 4) * 8;

  f32x4 acc[4][4] = {};
  const unsigned char* Ab = A + (size_t)(j0 + lrow) * NS + lkg;
  const unsigned char* Bb = B + (size_t)(i0 + lrow) * NS + lkg;
  long long a0[4], b0[4], a1[4], b1[4];
#pragma unroll
  for (int m = 0; m < 4; ++m) {
    a0[m] = *(const long long*)(Ab + (size_t)(m * 16) * NS);
    b0[m] = *(const long long*)(Bb + (size_t)(m * 16) * NS);
  }
  for (int kc = 0; kc < NS; kc += 64) {
#pragma unroll
    for (int m = 0; m < 4; ++m) {
      a1[m] = *(const long long*)(Ab + (size_t)(m * 16) * NS + kc + 32);
      b1[m] = *(const long long*)(Bb + (size_t)(m * 16) * NS + kc + 32);
    }
#pragma unroll
    for (int m = 0; m < 4; ++m)
#pragma unroll
      for (int n = 0; n < 4; ++n)
        acc[m][n] = __builtin_amdgcn_mfma_f32_16x16x32_fp8_fp8(a0[m], b0[n], acc[m][n], 0, 0, 0);
    if (kc + 64 < NS) {
#pragma unroll
      for (int m = 0; m < 4; ++m) {
        a0[m] = *(const long long*)(Ab + (size_t)(m * 16) * NS + kc + 64);
        b0[m] = *(const long long*)(Bb + (size_t)(m * 16) * NS + kc + 64);
      }
    }
#pragma unroll
    for (int m = 0; m < 4; ++m)
#pragma unroll
      for (int n = 0; n < 4; ++n)
        acc[m][n] = __builtin_amdgcn_mfma_f32_16x16x32_fp8_fp8(a1[m], b1[n], acc[m][n], 0, 0, 0);
  }
  const int orow = (lane >> 4) * 4;
#pragma unroll
  for (int m = 0; m < 4; ++m)
#pragma unroll
    for (int n = 0; n < 4; ++n)
#pragma unroll
      for (int r = 0; r < 4; ++r) {
        const int j = j0 + m * 16 + orow + r;
        const int i = i0 + n * 16 + lrow;
        C[(size_t)j * NS + i] = encf(acc[m][n][r] * (1.0f / 4096.0f));
      }
}

// sequential fallback (one product per launch)
__global__ void __launch_bounds__(256)
pairgemm_kernel(const unsigned char* __restrict__ A, const unsigned char* __restrict__ B,
                unsigned char* __restrict__ C) {
  pairgemm_body(A, B, C, blockIdx.x, blockIdx.y);
}

// batched: z = a*2+b -> A=R_b, B=M_a, C=Q8+z*16M
__global__ void __launch_bounds__(256)
pairgemm4_kernel(const unsigned char* __restrict__ R0, const unsigned char* __restrict__ R1,
                 const unsigned char* __restrict__ M0, const unsigned char* __restrict__ M1,
                 unsigned char* __restrict__ Q8) {
  const int z = blockIdx.z;
  const unsigned char* A = (z & 1) ? R1 : R0;
  const unsigned char* B = (z >> 1) ? M1 : M0;
  pairgemm_body(A, B, Q8 + (size_t)z * 16777216, blockIdx.x, blockIdx.y);
}

// ---- in-place per-row byte permute into the scan's layout ----
__global__ void permq8_kernel(unsigned char* __restrict__ Q) {
  unsigned char* row = Q + ((size_t)blockIdx.y * NS + blockIdx.x) * NS;
  const int t = threadIdx.x;
  const int q = t >> 6, l = t & 63;
  uint4 o;
  o.x = *(const unsigned*)(row + q * 1024 + 0 * 256 + l * 4);
  o.y = *(const unsigned*)(row + q * 1024 + 1 * 256 + l * 4);
  o.z = *(const unsigned*)(row + q * 1024 + 2 * 256 + l * 4);
  o.w = *(const unsigned*)(row + q * 1024 + 3 * 256 + l * 4);
  *(uint4*)(row + q * 1024 + l * 16) = o;
}

// ---- normalize O (f32) ----
__global__ void onnorm_kernel(const float* __restrict__ O, float* __restrict__ On) {
  const int r = blockIdx.x * blockDim.x + threadIdx.x;
  if (r >= NS * 2) return;
  float4 v = *(const float4*)(O + (size_t)r * 4);
  float mx = fmaxf(fmaxf(v.x, v.y), fmaxf(v.z, v.w));
  float e0 = __expf(v.x - mx), e1 = __expf(v.y - mx), e2 = __expf(v.z - mx), e3 = __expf(v.w - mx);
  float inv = 1.0f / (e0 + e1 + e2 + e3);
  *(float4*)(On + (size_t)r * 4) = make_float4(e0 * inv, e1 * inv, e2 * inv, e3 * inv);
}

// ---- E_{a,b}[i][c] = sum_k Tn[i,a,k] * On[k,b,c] ----
__global__ void emat_kernel(const float* __restrict__ T, const float2* __restrict__ rstat,
                            const float* __restrict__ On, float* __restrict__ E) {
  const int i = blockIdx.x, a = blockIdx.y;
  const int r = i * 2 + a;
  const float2 st = rstat[r];
  const int tid = threadIdx.x;
  float e0[4] = {}, e1[4] = {};
  for (int q = 0; q < 16; ++q) {
    const int k = q * 256 + tid;
    const float w = __expf(T[(size_t)r * NS + k] - st.x) * st.y * (1.0f / 4096.0f);
    const float4 o0 = *(const float4*)(On + (size_t)(k * 2 + 0) * 4);
    const float4 o1 = *(const float4*)(On + (size_t)(k * 2 + 1) * 4);
    e0[0] += w * o0.x; e0[1] += w * o0.y; e0[2] += w * o0.z; e0[3] += w * o0.w;
    e1[0] += w * o1.x; e1[1] += w * o1.y; e1[2] += w * o1.z; e1[3] += w * o1.w;
  }
  __shared__ float red[4][8];
  const int lane = tid & 63, wave = tid >> 6;
#pragma unroll
  for (int c = 0; c < 4; ++c) { e0[c] = wred_sum(e0[c]); e1[c] = wred_sum(e1[c]); }
  if (lane == 0) {
#pragma unroll
    for (int c = 0; c < 4; ++c) { red[wave][c] = e0[c]; red[wave][4 + c] = e1[c]; }
  }
  __syncthreads();
  if (tid == 0) {
    float f0[4], f1[4];
#pragma unroll
    for (int c = 0; c < 4; ++c) {
      f0[c] = red[0][c] + red[1][c] + red[2][c] + red[3][c];
      f1[c] = red[0][4 + c] + red[1][4 + c] + red[2][4 + c] + red[3][4 + c];
    }
    *(float4*)(E + ((size_t)(a * 2 + 0) * NS + i) * 4) = make_float4(f0[0], f0[1], f0[2], f0[3]);
    *(float4*)(E + ((size_t)(a * 2 + 1) * NS + i) * 4) = make_float4(f1[0], f1[1], f1[2], f1[3]);
  }
}

// ---- s0 = softmax(init) * 4096 ----
__global__ void initstate_kernel(const float* __restrict__ init, float* __restrict__ s0) {
  const int tid = threadIdx.x;
  float4 v = *(const float4*)(init + tid * 4);
  float mx = fmaxf(fmaxf(v.x, v.y), fmaxf(v.z, v.w));
  __shared__ float red[16];
  mx = wred_max(mx);
  if ((tid & 63) == 0) red[tid >> 6] = mx;
  __syncthreads();
  float MX = -1e30f;
#pragma unroll
  for (int k = 0; k < 16; ++k) MX = fmaxf(MX, red[k]);
  __syncthreads();
  float e0 = __expf(v.x - MX), e1 = __expf(v.y - MX), e2 = __expf(v.z - MX), e3 = __expf(v.w - MX);
  float se = wred_sum(e0 + e1 + e2 + e3);
  if ((tid & 63) == 0) red[tid >> 6] = se;
  __syncthreads();
  float tot = 0.f;
#pragma unroll
  for (int k = 0; k < 16; ++k) tot += red[k];
  float inv = 4096.0f / tot;
  *(float4*)(s0 + tid * 4) = make_float4(e0 * inv, e1 * inv, e2 * inv, e3 * inv);
}

// ---- K3: pair-fused scan (R7 structure, best measured: 3.13us/round).
// 16 waves x 1 col; per-block epoch flags; relaxed WT state stores drained by
// __syncthreads before the relaxed flag store; readers poll flags then do
// first-touch cached loads of the fresh state row.
__global__ void __launch_bounds__(THR, 4)
scan_kernel(const unsigned char* __restrict__ Pt8, const int* __restrict__ seq,
            float* __restrict__ states, unsigned* __restrict__ flags) {
  __shared__ float smem[NS];
  __shared__ int spid[1024];
  const int tid = threadIdx.x;
  const int lane = tid & 63;
  const int wave = tid >> 6;
  const int blk = blockIdx.x;
  const int col = blk * 16 + wave;

  spid[tid] = seq[2 * tid] * 2 + seq[2 * tid + 1];
  __syncthreads();

  const unsigned* fp = flags + lane * 4;  // each lane watches 4 blocks

  uint4 qa0, qa1, qa2, qa3, qb0, qb1, qb2, qb3;
  {
    const unsigned char* cb = Pt8 + ((size_t)spid[0] * NS + col) * NS + lane * 16;
    qa0 = *(const uint4*)(cb);
    qa1 = *(const uint4*)(cb + 1024);
    qa2 = *(const uint4*)(cb + 2048);
    qa3 = *(const uint4*)(cb + 3072);
  }

  for (int u = 0; u < NT; ++u) {
    // (a) prefetch next pair-matrix columns (overlaps the wait)
    if (u + 1 < NT) {
      const unsigned char* cb = Pt8 + ((size_t)spid[u + 1] * NS + col) * NS + lane * 16;
      qb0 = *(const uint4*)(cb);
      qb1 = *(const uint4*)(cb + 1024);
      qb2 = *(const uint4*)(cb + 2048);
      qb3 = *(const uint4*)(cb + 3072);
    }

    // (b) wait for epoch u
    if (u > 0) {
      if (wave == 0) {
        const unsigned tgt = (unsigned)u;
        unsigned f0, f1, f2, f3;
        do {
          f0 = __hip_atomic_load(fp + 0, __ATOMIC_RELAXED, __HIP_MEMORY_SCOPE_AGENT);
          f1 = __hip_atomic_load(fp + 1, __ATOMIC_RELAXED, __HIP_MEMORY_SCOPE_AGENT);
          f2 = __hip_atomic_load(fp + 2, __ATOMIC_RELAXED, __HIP_MEMORY_SCOPE_AGENT);
          f3 = __hip_atomic_load(fp + 3, __ATOMIC_RELAXED, __HIP_MEMORY_SCOPE_AGENT);
        } while (!__all(f0 >= tgt && f1 >= tgt && f2 >= tgt && f3 >= tgt));
      }
      __syncthreads();
    }

    // (c) stage state u -> LDS (first-touch cached loads, fresh row)
    const float* s = states + (size_t)u * NS;
    *(float4*)(smem + tid * 4) = *(const float4*)(s + tid * 4);
    __syncthreads();

    // (d) compute
    float a = 0.f;
#define DOQ(Q, qi)                                                     \
    {                                                                  \
      float4 s0 = *(const float4*)(smem + qi * 1024 + lane * 4);       \
      float4 s1 = *(const float4*)(smem + qi * 1024 + 256 + lane * 4); \
      float4 s2 = *(const float4*)(smem + qi * 1024 + 512 + lane * 4); \
      float4 s3 = *(const float4*)(smem + qi * 1024 + 768 + lane * 4); \
      a = dot4_fp8(Q.x, s0, a);                                        \
      a = dot4_fp8(Q.y, s1, a);                                        \
      a = dot4_fp8(Q.z, s2, a);                                        \
      a = dot4_fp8(Q.w, s3, a);                                        \
    }
    DOQ(qa0, 0) DOQ(qa1, 1) DOQ(qa2, 2) DOQ(qa3, 3)
#undef DOQ

    a = wred_sum(a);
    if (lane == 0) {
      __hip_atomic_store(&states[(size_t)(u + 1) * NS + col], a * (1.0f / 4096.0f),
                         __ATOMIC_RELAXED, __HIP_MEMORY_SCOPE_AGENT);
    }
    __syncthreads();  // vmcnt(0): all waves' WT stores acked before signal
    if (tid == 0) {
      __hip_atomic_store(&flags[blk], (unsigned)(u + 1),
                         __ATOMIC_RELAXED, __HIP_MEMORY_SCOPE_AGENT);
    }
    qa0 = qb0; qa1 = qb1; qa2 = qb2; qa3 = qb3;
  }
}

// ---- K4: even t: out = (s_u @ On[:,y])/mass; odd: (s_u @ E_ab)/mass ----
__global__ void output_kernel(const float* __restrict__ states, const float* __restrict__ On,
                              const float* __restrict__ E, const int* __restrict__ seq,
                              float* __restrict__ out) {
  const int t = blockIdx.x;
  const int y = seq[t];
  const int u = t >> 1;
  const bool odd = t & 1;
  const float* s = states + (size_t)u * NS;
  const float4* W = odd ? (const float4*)(E + ((size_t)(seq[t - 1] * 2 + y) * NS) * 4) : nullptr;
  const float4* Onf = (const float4*)On;
  const int tid = threadIdx.x;
  float a0 = 0, a1 = 0, a2 = 0, a3 = 0, mass = 0;
  for (int q = 0; q < 16; ++q) {
    const int i = q * 256 + tid;
    const float sv = s[i];
    const float4 w = odd ? W[i] : Onf[i * 2 + y];
    a0 += sv * w.x; a1 += sv * w.y; a2 += sv * w.z; a3 += sv * w.w; mass += sv;
  }
  a0 = wred_sum(a0); a1 = wred_sum(a1); a2 = wred_sum(a2); a3 = wred_sum(a3);
  mass = wred_sum(mass);
  __shared__ float red[4][5];
  const int lane = tid & 63, wave = tid >> 6;
  if (lane == 0) { red[wave][0] = a0; red[wave][1] = a1; red[wave][2] = a2;
                   red[wave][3] = a3; red[wave][4] = mass; }
  __syncthreads();
  if (tid == 0) {
    float b0 = red[0][0] + red[1][0] + red[2][0] + red[3][0];
    float b1 = red[0][1] + red[1][1] + red[2][1] + red[3][1];
    float b2 = red[0][2] + red[1][2] + red[2][2] + red[3][2];
    float b3 = red[0][3] + red[1][3] + red[2][3] + red[3][3];
    float M  = red[0][4] + red[1][4] + red[2][4] + red[3][4];
    const float inv = 1.0f / M;
    *(float4*)(out + (size_t)t * 4) = make_float4(b0 * inv, b1 * inv, b2 * inv, b3 * inv);
  }
}

extern "C" void kernel_launch(void* const* d_in, const int* in_sizes, int n_in,
                              void* d_out, int out_size, void* d_ws, size_t ws_size,
                              hipStream_t stream) {
  const int* seq    = (const int*)d_in[0];
  const float* T    = (const float*)d_in[1];
  const float* O    = (const float*)d_in[2];
  const float* init = (const float*)d_in[3];
  float* out = (float*)d_out;

  char* ws = (char*)d_ws;
  const size_t MB16 = 16777216;
  const bool big = ws_size >= (size_t)134677504;  // 128 MiB + small tables

  unsigned char *Q8, *R0, *R1, *M0, *M1;
  float* states;
  char* sm;
  if (big) {
    // Q8 [0,64M) | R0 [64,80) R1 [80,96) M0 [96,112) M1 [112,128) | sm 128M+
    Q8 = (unsigned char*)ws;
    R0 = (unsigned char*)(ws + 4 * MB16);
    R1 = (unsigned char*)(ws + 5 * MB16);
    M0 = (unsigned char*)(ws + 6 * MB16);
    M1 = (unsigned char*)(ws + 7 * MB16);
    states = (float*)(ws + 4 * MB16);  // overlays R0/R1 after GEMMs (32M)
    sm = ws + 8 * MB16;
  } else {
    // fallback (proven 101M): Rcur[0,16) Mcur[16,32) Q8[32,96) sm 96M+
    R0 = (unsigned char*)ws;           // Rcur
    M0 = (unsigned char*)(ws + MB16);  // Mcur
    R1 = R0; M1 = M0;                  // rebuilt per product
    Q8 = (unsigned char*)(ws + 2 * MB16);
    states = (float*)ws;
    sm = ws + 6 * MB16;
  }
  float* On      = (float*)(sm);
  float2* rstat  = (float2*)(sm + 131072);
  float* E       = (float*)(sm + 131072 + 65536);
  unsigned* flags = (unsigned*)(sm + 131072 + 65536 + 262144);

  (void)hipMemsetAsync(flags, 0, NBLK * 4, stream);
  hipLaunchKernelGGL(rowstats_kernel, dim3(NS * 2), dim3(256), 0, stream, T, rstat);
  hipLaunchKernelGGL(onnorm_kernel, dim3(32), dim3(256), 0, stream, O, On);

  if (big) {
    hipLaunchKernelGGL(buildR_kernel, dim3(16, 256), dim3(256), 0, stream, T, rstat, R0, 0);
    hipLaunchKernelGGL(buildR_kernel, dim3(16, 256), dim3(256), 0, stream, T, rstat, R1, 1);
    hipLaunchKernelGGL(buildM_kernel, dim3(NS), dim3(256), 0, stream, T, rstat, M0, 0);
    hipLaunchKernelGGL(buildM_kernel, dim3(NS), dim3(256), 0, stream, T, rstat, M1, 1);
    hipLaunchKernelGGL(pairgemm4_kernel, dim3(32, 32, 4), dim3(256), 0, stream,
                       R0, R1, M0, M1, Q8);
  } else {
    hipLaunchKernelGGL(buildR_kernel, dim3(16, 256), dim3(256), 0, stream, T, rstat, R0, 0);
    hipLaunchKernelGGL(buildM_kernel, dim3(NS), dim3(256), 0, stream, T, rstat, M0, 0);
    hipLaunchKernelGGL(pairgemm_kernel, dim3(32, 32), dim3(256), 0, stream, R0, M0,
                       Q8 + (size_t)0 * MB16);  // a=0,b=0
    hipLaunchKernelGGL(buildM_kernel, dim3(NS), dim3(256), 0, stream, T, rstat, M0, 1);
    hipLaunchKernelGGL(pairgemm_kernel, dim3(32, 32), dim3(256), 0, stream, R0, M0,
                       Q8 + (size_t)2 * MB16);  // a=1,b=0
    hipLaunchKernelGGL(buildR_kernel, dim3(16, 256), dim3(256), 0, stream, T, rstat, R0, 1);
    hipLaunchKernelGGL(buildM_kernel, dim3(NS), dim3(256), 0, stream, T, rstat, M0, 0);
    hipLaunchKernelGGL(pairgemm_kernel, dim3(32, 32), dim3(256), 0, stream, R0, M0,
                       Q8 + (size_t)1 * MB16);  // a=0,b=1
    hipLaunchKernelGGL(buildM_kernel, dim3(NS), dim3(256), 0, stream, T, rstat, M0, 1);
    hipLaunchKernelGGL(pairgemm_kernel, dim3(32, 32), dim3(256), 0, stream, R0, M0,
                       Q8 + (size_t)3 * MB16);  // a=1,b=1
  }

  hipLaunchKernelGGL(permq8_kernel, dim3(NS, 4), dim3(256), 0, stream, Q8);
  hipLaunchKernelGGL(emat_kernel, dim3(NS, 2), dim3(256), 0, stream, T, rstat, On, E);
  hipLaunchKernelGGL(initstate_kernel, dim3(1), dim3(1024), 0, stream, init, states);

  void* kargs[] = { (void*)&Q8, (void*)&seq, (void*)&states, (void*)&flags };
  (void)hipLaunchCooperativeKernel((void*)scan_kernel, dim3(NBLK), dim3(THR),
                                   kargs, 0, stream);

  hipLaunchKernelGGL(output_kernel, dim3(SEQ), dim3(256), 0, stream, states, On, E, seq, out);
}